// Round 2
// baseline (237.191 us; speedup 1.0000x reference)
//
#include <hip/hip_runtime.h>
#include <math.h>

#define L_TOTAL 65536
#define D_DIM   256
#define C_ROWS  128              // rows per chunk
#define N_CHUNK (L_TOTAL / C_ROWS)   // 512

// ---------------- Pass 1: per-chunk aggregates -----------------------------
// s[i] = <K[i], q>; aggregate (m_c, u_c, w_c[D]) per chunk of 128 rows.
__global__ __launch_bounds__(256) void k1_aggregate(
    const float* __restrict__ K, const float* __restrict__ V,
    const float* __restrict__ q,
    float* __restrict__ s_g, float* __restrict__ cm,
    float* __restrict__ cu, float* __restrict__ cw)
{
    const int t = threadIdx.x;            // 0..255
    const int c = blockIdx.x;             // chunk
    const int r0 = c * C_ROWS;
    const int wave = t >> 6, lane = t & 63;

    __shared__ float s_lds[C_ROWS];
    __shared__ float red[C_ROWS];
    __shared__ float coef[C_ROWS];

    // each lane owns q[4*lane .. 4*lane+3]
    const float4 q4 = *reinterpret_cast<const float4*>(q + 4 * lane);

    // wave-per-row dot products: wave w handles rows [r0+32w, r0+32w+32)
    for (int k = 0; k < 32; ++k) {
        const int row = r0 + wave * 32 + k;
        const float4 kv = *reinterpret_cast<const float4*>(K + (size_t)row * D_DIM + 4 * lane);
        float d = kv.x * q4.x + kv.y * q4.y + kv.z * q4.z + kv.w * q4.w;
        #pragma unroll
        for (int off = 32; off > 0; off >>= 1) d += __shfl_xor(d, off, 64);
        if (lane == 0) s_lds[wave * 32 + k] = d;
    }
    __syncthreads();

    if (t < C_ROWS) { s_g[r0 + t] = s_lds[t]; red[t] = s_lds[t]; }
    __syncthreads();
    // max reduce over 128
    for (int off = 64; off > 0; off >>= 1) {
        if (t < off) red[t] = fmaxf(red[t], red[t + off]);
        __syncthreads();
    }
    const float m_c = red[0];
    __syncthreads();
    if (t < C_ROWS) { coef[t] = __expf(s_lds[t] - m_c); red[t] = coef[t]; }
    __syncthreads();
    for (int off = 64; off > 0; off >>= 1) {
        if (t < off) red[t] += red[t + off];
        __syncthreads();
    }
    const float u_c = red[0];

    // w_c[d] = sum_j coef[j] * V[r0+j][d]; thread t = dim t
    float w = 0.f;
    const float* Vp = V + (size_t)r0 * D_DIM + t;
    #pragma unroll 8
    for (int j = 0; j < C_ROWS; ++j)
        w = fmaf(coef[j], Vp[(size_t)j * D_DIM], w);

    cw[(size_t)c * D_DIM + t] = w;
    if (t == 0) { cm[c] = m_c; cu[c] = u_c; }
}

// ---------------- Pass 2: scan over chunk aggregates -----------------------
// Scalar (m,u) scan over 512 chunks via pair-combine + Hillis-Steele (all
// blocks redundantly), then each block streams the exclusive vector prefix
// pw for a 64-dim slice.
__global__ __launch_bounds__(256) void k2_scan(
    const float* __restrict__ cm, const float* __restrict__ cu,
    const float* __restrict__ cw,
    float* __restrict__ pm, float* __restrict__ pu, float* __restrict__ pw)
{
    const int t = threadIdx.x;  // 0..255 ; owns chunk pair (2t, 2t+1)
    __shared__ float Lm[256], Lu[256];
    __shared__ float Acoef[N_CHUNK], Bcoef[N_CHUNK];

    const float m0 = cm[2 * t], u0 = cu[2 * t];
    const float m1 = cm[2 * t + 1], u1 = cu[2 * t + 1];
    // pair aggregate
    const float mp = fmaxf(m0, m1);
    const float up = u0 * __expf(m0 - mp) + u1 * __expf(m1 - mp);
    Lm[t] = mp; Lu[t] = up;
    float M = mp, U = up;
    __syncthreads();
    for (int off = 1; off < 256; off <<= 1) {
        float mm1 = 0.f, uu1 = 0.f;
        const bool act = (t >= off);
        if (act) { mm1 = Lm[t - off]; uu1 = Lu[t - off]; }
        __syncthreads();
        if (act) {
            const float mm = fmaxf(mm1, M);
            U = uu1 * __expf(mm1 - mm) + U * __expf(M - mm);
            M = mm;
            Lm[t] = M; Lu[t] = U;
        }
        __syncthreads();
    }
    // exclusive pair prefix = prefix of chunk 2t
    const float Me = (t == 0) ? -INFINITY : Lm[t - 1];
    const float Ue = (t == 0) ? 0.f : Lu[t - 1];
    // inclusive through chunk 2t = prefix of chunk 2t+1
    const float Mx = fmaxf(Me, m0);
    const float Ux = Ue * __expf(Me - Mx) + u0 * __expf(m0 - Mx);
    // inclusive through chunk 2t+1 (max only, for coefficients)
    const float My = fmaxf(Mx, m1);

    Acoef[2 * t]     = __expf(Me - Mx);   // t==0: exp(-inf)=0
    Bcoef[2 * t]     = __expf(m0 - Mx);
    Acoef[2 * t + 1] = __expf(Mx - My);
    Bcoef[2 * t + 1] = __expf(m1 - My);

    if (blockIdx.x == 0) {
        pm[2 * t] = Me;  pu[2 * t] = Ue;
        pm[2 * t + 1] = Mx; pu[2 * t + 1] = Ux;
    }
    __syncthreads();

    // vector prefix for this block's 64-dim slice
    if (t < 64) {
        const int d = blockIdx.x * 64 + t;
        float W = 0.f;
        #pragma unroll 8
        for (int c2 = 0; c2 < N_CHUNK; ++c2) {
            const float wv = cw[(size_t)c2 * D_DIM + d];
            pw[(size_t)c2 * D_DIM + d] = W;
            W = W * Acoef[c2] + wv * Bcoef[c2];
        }
    }
}

// ---------------- Pass 3: seeded local scan + output -----------------------
__global__ __launch_bounds__(256) void k3_output(
    const float* __restrict__ V, const float* __restrict__ s_g,
    const float* __restrict__ pm, const float* __restrict__ pu,
    const float* __restrict__ pw, float* __restrict__ out)
{
    const int t = threadIdx.x;
    const int c = blockIdx.x;
    const int r0 = c * C_ROWS;

    __shared__ float sm[C_ROWS], su[C_ROWS];
    __shared__ float sa[C_ROWS], se[C_ROWS], sri[C_ROWS];

    float sv = 0.f;
    if (t < C_ROWS) {
        sv = s_g[r0 + t];
        sm[t] = sv; su[t] = 1.f;
    }
    float m = sv, u = 1.f;
    __syncthreads();
    for (int off = 1; off < C_ROWS; off <<= 1) {
        float m1 = 0.f, u1 = 0.f;
        const bool act = (t >= off) && (t < C_ROWS);
        if (act) { m1 = sm[t - off]; u1 = su[t - off]; }
        __syncthreads();
        if (act) {
            const float mm = fmaxf(m1, m);
            u = u1 * __expf(m1 - mm) + u * __expf(m - mm);
            m = mm;
            sm[t] = m; su[t] = u;
        }
        __syncthreads();
    }
    if (t < C_ROWS) {
        const float Mh = pm[c], Uh = pu[c];
        const float msd = fmaxf(Mh, m);
        const float usd = Uh * __expf(Mh - msd) + u * __expf(m - msd);
        const float mprev = (t == 0) ? Mh : fmaxf(Mh, sm[t - 1]);
        sa[t]  = __expf(mprev - msd);   // chunk 0, row 0: exp(-inf)=0
        se[t]  = __expf(sv - msd);
        sri[t] = 1.0f / usd;
    }
    __syncthreads();

    // vector recurrence: thread t = dim t
    float W = pw[(size_t)c * D_DIM + t];
    const float* Vp = V + (size_t)r0 * D_DIM + t;
    float* Op = out + (size_t)r0 * D_DIM + t;
    #pragma unroll 4
    for (int j = 0; j < C_ROWS; ++j) {
        const float v = Vp[(size_t)j * D_DIM];
        W = W * sa[j] + v * se[j];
        Op[(size_t)j * D_DIM] = W * sri[j];
    }
}

extern "C" void kernel_launch(void* const* d_in, const int* in_sizes, int n_in,
                              void* d_out, int out_size, void* d_ws, size_t ws_size,
                              hipStream_t stream) {
    const float* K = (const float*)d_in[0];
    const float* V = (const float*)d_in[1];
    const float* q = (const float*)d_in[2];
    float* out = (float*)d_out;

    float* ws = (float*)d_ws;
    float* s_g = ws;                            // 65536
    float* cm  = ws + L_TOTAL;                  // 512
    float* cu  = cm + N_CHUNK;                  // 512
    float* cw  = cu + N_CHUNK;                  // 512*256 = 131072
    float* pm  = cw + (size_t)N_CHUNK * D_DIM;  // 512
    float* pu  = pm + N_CHUNK;                  // 512
    float* pw  = pu + N_CHUNK;                  // 131072

    k1_aggregate<<<N_CHUNK, 256, 0, stream>>>(K, V, q, s_g, cm, cu, cw);
    k2_scan<<<4, 256, 0, stream>>>(cm, cu, cw, pm, pu, pw);
    k3_output<<<N_CHUNK, 256, 0, stream>>>(V, s_g, pm, pu, pw, out);
}

// Round 3
// 202.081 us; speedup vs baseline: 1.1737x; 1.1737x over previous
//
#include <hip/hip_runtime.h>
#include <math.h>

#define L_TOTAL 65536
#define D_DIM   256
#define C_ROWS  32                    // rows per chunk
#define N_CHUNK (L_TOTAL / C_ROWS)    // 2048
#define SUPER   32                    // chunks per super-chunk
#define N_SUPER (N_CHUNK / SUPER)     // 64

// ---------------- kA: per-chunk aggregates ---------------------------------
// Chunk c (32 rows): s[i]=<K[i],q>; m_c=max s; u_c=sum exp(s-m_c);
// w_c[d]=sum exp(s-m_c)*V[i][d].
__global__ __launch_bounds__(256) void kA_aggregate(
    const float* __restrict__ K, const float* __restrict__ V,
    const float* __restrict__ q,
    float* __restrict__ s_g, float* __restrict__ cm,
    float* __restrict__ cu, float* __restrict__ cw)
{
    const int t = threadIdx.x;
    const int c = blockIdx.x;
    const int r0 = c * C_ROWS;
    const int wave = t >> 6, lane = t & 63;

    __shared__ float s_lds[C_ROWS];
    __shared__ float red[C_ROWS];
    __shared__ float coef[C_ROWS];

    const float4 q4 = *reinterpret_cast<const float4*>(q + 4 * lane);

    // wave w handles rows [8w, 8w+8): issue all 8 loads, then reduce
    float4 kv[8];
    #pragma unroll
    for (int k = 0; k < 8; ++k) {
        const int row = r0 + wave * 8 + k;
        kv[k] = *reinterpret_cast<const float4*>(K + (size_t)row * D_DIM + 4 * lane);
    }
    #pragma unroll
    for (int k = 0; k < 8; ++k) {
        float d = kv[k].x * q4.x + kv[k].y * q4.y + kv[k].z * q4.z + kv[k].w * q4.w;
        #pragma unroll
        for (int off = 32; off > 0; off >>= 1) d += __shfl_xor(d, off, 64);
        if (lane == 0) s_lds[wave * 8 + k] = d;
    }
    __syncthreads();

    if (t < C_ROWS) { s_g[r0 + t] = s_lds[t]; red[t] = s_lds[t]; }
    __syncthreads();
    for (int off = 16; off > 0; off >>= 1) {
        if (t < off) red[t] = fmaxf(red[t], red[t + off]);
        __syncthreads();
    }
    const float m_c = red[0];
    __syncthreads();
    if (t < C_ROWS) { coef[t] = __expf(s_lds[t] - m_c); red[t] = coef[t]; }
    __syncthreads();
    for (int off = 16; off > 0; off >>= 1) {
        if (t < off) red[t] += red[t + off];
        __syncthreads();
    }
    const float u_c = red[0];

    // w_c[d]: thread t = dim t
    float w = 0.f;
    const float* Vp = V + (size_t)r0 * D_DIM + t;
    #pragma unroll 8
    for (int j = 0; j < C_ROWS; ++j)
        w = fmaf(coef[j], Vp[(size_t)j * D_DIM], w);

    cw[(size_t)c * D_DIM + t] = w;
    if (t == 0) { cm[c] = m_c; cu[c] = u_c; }
}

// ---------------- kB: scalar (m,u) scan over 2048 chunks -------------------
// One block, 256 threads x 8 chunks each. Writes exclusive prefixes pm/pu
// [0..2047] plus pm[2048]/pu[2048] = global inclusive total.
__global__ __launch_bounds__(256) void kB_scalar_scan(
    const float* __restrict__ cm, const float* __restrict__ cu,
    float* __restrict__ pm, float* __restrict__ pu)
{
    const int t = threadIdx.x;
    __shared__ float Lm[256], Lu[256];

    float am[8], au[8];
    float M = -INFINITY, U = 0.f;
    #pragma unroll
    for (int j = 0; j < 8; ++j) {
        am[j] = cm[8 * t + j]; au[j] = cu[8 * t + j];
        const float mm = fmaxf(M, am[j]);
        U = U * __expf(M - mm) + au[j] * __expf(am[j] - mm);
        M = mm;
    }
    Lm[t] = M; Lu[t] = U;
    float Mi = M, Ui = U;
    __syncthreads();
    for (int off = 1; off < 256; off <<= 1) {
        float m1 = 0.f, u1 = 0.f;
        const bool act = (t >= off);
        if (act) { m1 = Lm[t - off]; u1 = Lu[t - off]; }
        __syncthreads();
        if (act) {
            const float mm = fmaxf(m1, Mi);
            Ui = u1 * __expf(m1 - mm) + Ui * __expf(Mi - mm);
            Mi = mm;
            Lm[t] = Mi; Lu[t] = Ui;
        }
        __syncthreads();
    }
    float Me = (t == 0) ? -INFINITY : Lm[t - 1];
    float Ue = (t == 0) ? 0.f : Lu[t - 1];
    #pragma unroll
    for (int j = 0; j < 8; ++j) {
        pm[8 * t + j] = Me; pu[8 * t + j] = Ue;
        const float mm = fmaxf(Me, am[j]);
        Ue = Ue * __expf(Me - mm) + au[j] * __expf(am[j] - mm);
        Me = mm;
    }
    if (t == 255) { pm[N_CHUNK] = Me; pu[N_CHUNK] = Ue; }
}

// ---------------- kC: within-super vector scans ----------------------------
// Block S: for its 32 chunks, exclusive vector prefix pwl[c] (frame pm[c])
// restricted to chunks inside S; tail T[S] (frame pm[32(S+1)]).
__global__ __launch_bounds__(256) void kC_super_scan(
    const float* __restrict__ cm, const float* __restrict__ cw,
    const float* __restrict__ pm,
    float* __restrict__ pwl, float* __restrict__ T)
{
    const int t = threadIdx.x;   // dim
    const int S = blockIdx.x;
    __shared__ float ca[SUPER], cb[SUPER];

    if (t < SUPER) {
        const int c = S * SUPER + t;
        ca[t] = __expf(pm[c] - pm[c + 1]);   // c=0: exp(-inf)=0
        cb[t] = __expf(cm[c] - pm[c + 1]);
    }
    __syncthreads();

    float PW = 0.f;
    #pragma unroll 4
    for (int j = 0; j < SUPER; ++j) {
        const int c = S * SUPER + j;
        pwl[(size_t)c * D_DIM + t] = PW;
        const float wv = cw[(size_t)c * D_DIM + t];
        PW = PW * ca[j] + wv * cb[j];
    }
    T[(size_t)S * D_DIM + t] = PW;
}

// ---------------- kD: across-super vector scan -----------------------------
// sw[S] = exclusive vector prefix over supers < S, frame pm[32S].
__global__ __launch_bounds__(256) void kD_top_scan(
    const float* __restrict__ pm, const float* __restrict__ T,
    float* __restrict__ sw)
{
    const int t = threadIdx.x;   // dim
    float SW = 0.f;
    for (int S = 0; S < N_SUPER; ++S) {
        sw[(size_t)S * D_DIM + t] = SW;
        const float g = __expf(pm[S * SUPER] - pm[(S + 1) * SUPER]); // S=0: 0
        SW = SW * g + T[(size_t)S * D_DIM + t];
    }
}

// ---------------- kF: seeded local scan + output ---------------------------
__global__ __launch_bounds__(256) void kF_output(
    const float* __restrict__ V, const float* __restrict__ s_g,
    const float* __restrict__ pm, const float* __restrict__ pu,
    const float* __restrict__ pwl, const float* __restrict__ sw,
    float* __restrict__ out)
{
    const int t = threadIdx.x;
    const int c = blockIdx.x;
    const int S = c / SUPER;
    const int r0 = c * C_ROWS;

    __shared__ float sm[C_ROWS], su[C_ROWS];
    __shared__ float sa[C_ROWS], se[C_ROWS], sri[C_ROWS];

    float sv = 0.f;
    if (t < C_ROWS) {
        sv = s_g[r0 + t];
        sm[t] = sv; su[t] = 1.f;
    }
    float m = sv, u = 1.f;
    __syncthreads();
    for (int off = 1; off < C_ROWS; off <<= 1) {
        float m1 = 0.f, u1 = 0.f;
        const bool act = (t >= off) && (t < C_ROWS);
        if (act) { m1 = sm[t - off]; u1 = su[t - off]; }
        __syncthreads();
        if (act) {
            const float mm = fmaxf(m1, m);
            u = u1 * __expf(m1 - mm) + u * __expf(m - mm);
            m = mm;
            sm[t] = m; su[t] = u;
        }
        __syncthreads();
    }
    const float pmc = pm[c];
    if (t < C_ROWS) {
        const float puc = pu[c];
        const float mrow = fmaxf(pmc, m);
        const float urow = puc * __expf(pmc - mrow) + u * __expf(m - mrow);
        const float mprev = (t == 0) ? pmc : fmaxf(pmc, sm[t - 1]);
        sa[t]  = __expf(mprev - mrow);
        se[t]  = __expf(sv - mrow);
        sri[t] = 1.0f / urow;
    }
    __syncthreads();

    // W seed: global exclusive vector prefix in frame pm[c]
    const float g = (c == 0) ? 0.f : __expf(pm[S * SUPER] - pmc);
    float W = sw[(size_t)S * D_DIM + t] * g + pwl[(size_t)c * D_DIM + t];

    const float* Vp = V + (size_t)r0 * D_DIM + t;
    float* Op = out + (size_t)r0 * D_DIM + t;
    #pragma unroll 8
    for (int j = 0; j < C_ROWS; ++j) {
        const float v = Vp[(size_t)j * D_DIM];
        W = W * sa[j] + v * se[j];
        Op[(size_t)j * D_DIM] = W * sri[j];
    }
}

extern "C" void kernel_launch(void* const* d_in, const int* in_sizes, int n_in,
                              void* d_out, int out_size, void* d_ws, size_t ws_size,
                              hipStream_t stream) {
    const float* K = (const float*)d_in[0];
    const float* V = (const float*)d_in[1];
    const float* q = (const float*)d_in[2];
    float* out = (float*)d_out;

    float* ws  = (float*)d_ws;
    float* s_g = ws;                                  // 65536
    float* cm  = s_g + L_TOTAL;                       // 2048
    float* cu  = cm + N_CHUNK;                        // 2048
    float* pm  = cu + N_CHUNK;                        // 2049 (+pad)
    float* pu  = pm + (N_CHUNK + 16);                 // 2049 (+pad)
    float* cw  = pu + (N_CHUNK + 16);                 // 2048*256
    float* pwl = cw + (size_t)N_CHUNK * D_DIM;        // 2048*256
    float* T   = pwl + (size_t)N_CHUNK * D_DIM;       // 64*256
    float* sw  = T + (size_t)N_SUPER * D_DIM;         // 64*256

    kA_aggregate<<<N_CHUNK, 256, 0, stream>>>(K, V, q, s_g, cm, cu, cw);
    kB_scalar_scan<<<1, 256, 0, stream>>>(cm, cu, pm, pu);
    kC_super_scan<<<N_SUPER, 256, 0, stream>>>(cm, cw, pm, pwl, T);
    kD_top_scan<<<1, 256, 0, stream>>>(pm, T, sw);
    kF_output<<<N_CHUNK, 256, 0, stream>>>(V, s_g, pm, pu, pwl, sw, out);
}

// Round 4
// 194.632 us; speedup vs baseline: 1.2187x; 1.0383x over previous
//
#include <hip/hip_runtime.h>
#include <math.h>

#define L_TOTAL 65536
#define D_DIM   256
#define C_ROWS  32                    // rows per chunk
#define N_CHUNK (L_TOTAL / C_ROWS)    // 2048
#define SUPER   32                    // chunks per super-chunk
#define N_SUPER (N_CHUNK / SUPER)     // 64

// ---------------- kA: per-chunk aggregates ---------------------------------
// One barrier. 16 KB of loads in flight per wave before any dependent op.
__global__ __launch_bounds__(256) void kA_aggregate(
    const float* __restrict__ K, const float* __restrict__ V,
    const float* __restrict__ q,
    float* __restrict__ s_g, float* __restrict__ cm,
    float* __restrict__ cu, float* __restrict__ cw)
{
    const int t = threadIdx.x;
    const int c = blockIdx.x;
    const int r0 = c * C_ROWS;
    const int wave = t >> 6, lane = t & 63;

    __shared__ float s_lds[C_ROWS];

    // V loads first: thread t = dim t, 32 independent b32 loads
    float v[C_ROWS];
    const float* Vp = V + (size_t)r0 * D_DIM + t;
    #pragma unroll
    for (int j = 0; j < C_ROWS; ++j) v[j] = Vp[(size_t)j * D_DIM];

    // K loads: wave-per-row, 8 rows per wave, 8 independent b128 loads
    const float4 q4 = *reinterpret_cast<const float4*>(q + 4 * lane);
    const float* Kp = K + (size_t)(r0 + wave * 8) * D_DIM + 4 * lane;
    float4 kv[8];
    #pragma unroll
    for (int k = 0; k < 8; ++k)
        kv[k] = *reinterpret_cast<const float4*>(Kp + (size_t)k * D_DIM);

    #pragma unroll
    for (int k = 0; k < 8; ++k) {
        float d = kv[k].x * q4.x + kv[k].y * q4.y + kv[k].z * q4.z + kv[k].w * q4.w;
        #pragma unroll
        for (int off = 32; off > 0; off >>= 1) d += __shfl_xor(d, off, 64);
        if (lane == 0) s_lds[wave * 8 + k] = d;
    }
    __syncthreads();   // the only barrier

    if (t < C_ROWS) s_g[r0 + t] = s_lds[t];

    // redundant per-thread reduction from LDS broadcast reads
    float m_c = -INFINITY;
    #pragma unroll
    for (int j = 0; j < C_ROWS; ++j) m_c = fmaxf(m_c, s_lds[j]);

    float u_c = 0.f, w = 0.f;
    #pragma unroll
    for (int j = 0; j < C_ROWS; ++j) {
        const float cf = __expf(s_lds[j] - m_c);
        u_c += cf;
        w = fmaf(cf, v[j], w);
    }

    cw[(size_t)c * D_DIM + t] = w;
    if (t == 0) { cm[c] = m_c; cu[c] = u_c; }
}

// ---------------- kB: scalar (m,u) scan over 2048 chunks -------------------
__global__ __launch_bounds__(256) void kB_scalar_scan(
    const float* __restrict__ cm, const float* __restrict__ cu,
    float* __restrict__ pm, float* __restrict__ pu)
{
    const int t = threadIdx.x;
    __shared__ float Lm[256], Lu[256];

    float am[8], au[8];
    float M = -INFINITY, U = 0.f;
    #pragma unroll
    for (int j = 0; j < 8; ++j) {
        am[j] = cm[8 * t + j]; au[j] = cu[8 * t + j];
        const float mm = fmaxf(M, am[j]);
        U = U * __expf(M - mm) + au[j] * __expf(am[j] - mm);
        M = mm;
    }
    Lm[t] = M; Lu[t] = U;
    float Mi = M, Ui = U;
    __syncthreads();
    for (int off = 1; off < 256; off <<= 1) {
        float m1 = 0.f, u1 = 0.f;
        const bool act = (t >= off);
        if (act) { m1 = Lm[t - off]; u1 = Lu[t - off]; }
        __syncthreads();
        if (act) {
            const float mm = fmaxf(m1, Mi);
            Ui = u1 * __expf(m1 - mm) + Ui * __expf(Mi - mm);
            Mi = mm;
            Lm[t] = Mi; Lu[t] = Ui;
        }
        __syncthreads();
    }
    float Me = (t == 0) ? -INFINITY : Lm[t - 1];
    float Ue = (t == 0) ? 0.f : Lu[t - 1];
    #pragma unroll
    for (int j = 0; j < 8; ++j) {
        pm[8 * t + j] = Me; pu[8 * t + j] = Ue;
        const float mm = fmaxf(Me, am[j]);
        Ue = Ue * __expf(Me - mm) + au[j] * __expf(am[j] - mm);
        Me = mm;
    }
    if (t == 255) { pm[N_CHUNK] = Me; pu[N_CHUNK] = Ue; }
}

// ---------------- kC: within-super vector scans (fully prefetched) ---------
__global__ __launch_bounds__(256) void kC_super_scan(
    const float* __restrict__ cm, const float* __restrict__ cw,
    const float* __restrict__ pm,
    float* __restrict__ pwl, float* __restrict__ T)
{
    const int t = threadIdx.x;   // dim
    const int S = blockIdx.x;
    __shared__ float ca[SUPER], cb[SUPER];

    // prefetch all 32 cw values (independent loads)
    float wv[SUPER];
    const float* cwp = cw + (size_t)S * SUPER * D_DIM + t;
    #pragma unroll
    for (int j = 0; j < SUPER; ++j) wv[j] = cwp[(size_t)j * D_DIM];

    if (t < SUPER) {
        const int c = S * SUPER + t;
        ca[t] = __expf(pm[c] - pm[c + 1]);   // c=0: exp(-inf)=0
        cb[t] = __expf(cm[c] - pm[c + 1]);
    }
    __syncthreads();

    float PW = 0.f;
    float* pwlp = pwl + (size_t)S * SUPER * D_DIM + t;
    #pragma unroll
    for (int j = 0; j < SUPER; ++j) {
        pwlp[(size_t)j * D_DIM] = PW;
        PW = PW * ca[j] + wv[j] * cb[j];
    }
    T[(size_t)S * D_DIM + t] = PW;
}

// ---------------- kD: across-super vector scan (fully prefetched) ----------
__global__ __launch_bounds__(256) void kD_top_scan(
    const float* __restrict__ pm, const float* __restrict__ T,
    float* __restrict__ sw)
{
    const int t = threadIdx.x;   // dim
    __shared__ float g[N_SUPER];

    float tv[N_SUPER];
    #pragma unroll
    for (int S = 0; S < N_SUPER; ++S) tv[S] = T[(size_t)S * D_DIM + t];

    if (t < N_SUPER)
        g[t] = __expf(pm[t * SUPER] - pm[(t + 1) * SUPER]);  // S=0: exp(-inf)=0
    __syncthreads();

    float SW = 0.f;
    #pragma unroll
    for (int S = 0; S < N_SUPER; ++S) {
        sw[(size_t)S * D_DIM + t] = SW;
        SW = SW * g[S] + tv[S];
    }
}

// ---------------- kF: seeded local scan + output (one barrier) -------------
__global__ __launch_bounds__(256) void kF_output(
    const float* __restrict__ V, const float* __restrict__ s_g,
    const float* __restrict__ pm, const float* __restrict__ pu,
    const float* __restrict__ pwl, const float* __restrict__ sw,
    float* __restrict__ out)
{
    const int t = threadIdx.x;
    const int c = blockIdx.x;
    const int S = c / SUPER;
    const int r0 = c * C_ROWS;
    const int wave = t >> 6, lane = t & 63;

    __shared__ float sa[C_ROWS], se[C_ROWS], sri[C_ROWS];

    // V loads first: 32 independent b32 loads
    float v[C_ROWS];
    const float* Vp = V + (size_t)r0 * D_DIM + t;
    #pragma unroll
    for (int j = 0; j < C_ROWS; ++j) v[j] = Vp[(size_t)j * D_DIM];

    // seeds (independent loads)
    const float seed_pwl = pwl[(size_t)c * D_DIM + t];
    const float seed_sw  = sw[(size_t)S * D_DIM + t];
    const float pmc = pm[c];
    const float pmS = pm[S * SUPER];

    // wave 0: barrier-free shuffle scan over the 32 rows
    if (wave == 0) {
        const float puc = pu[c];
        float s_val = -INFINITY;
        if (lane < C_ROWS) s_val = s_g[r0 + lane];
        float m = s_val, u = 1.0f;
        #pragma unroll
        for (int off = 1; off < C_ROWS; off <<= 1) {
            const float m1 = __shfl_up(m, off, 32);
            const float u1 = __shfl_up(u, off, 32);
            if ((lane & 31) >= off) {
                const float mm = fmaxf(m1, m);
                u = u1 * __expf(m1 - mm) + u * __expf(m - mm);
                m = mm;
            }
        }
        const float m_row = fmaxf(pmc, m);
        const float u_row = puc * __expf(pmc - m_row) + u * __expf(m - m_row);
        const float m_prev_raw = __shfl_up(m_row, 1, 32);
        const float m_prev = ((lane & 31) == 0) ? pmc : m_prev_raw;
        if (lane < C_ROWS) {
            sa[lane]  = __expf(m_prev - m_row);   // row0 of chunk0: exp(-inf)=0
            se[lane]  = __expf(s_val - m_row);
            sri[lane] = 1.0f / u_row;
        }
    }
    __syncthreads();   // the only barrier

    const float gf = (c == 0) ? 0.f : __expf(pmS - pmc);
    float W = seed_sw * gf + seed_pwl;

    float* Op = out + (size_t)r0 * D_DIM + t;
    #pragma unroll
    for (int j = 0; j < C_ROWS; ++j) {
        W = W * sa[j] + v[j] * se[j];
        Op[(size_t)j * D_DIM] = W * sri[j];
    }
}

extern "C" void kernel_launch(void* const* d_in, const int* in_sizes, int n_in,
                              void* d_out, int out_size, void* d_ws, size_t ws_size,
                              hipStream_t stream) {
    const float* K = (const float*)d_in[0];
    const float* V = (const float*)d_in[1];
    const float* q = (const float*)d_in[2];
    float* out = (float*)d_out;

    float* ws  = (float*)d_ws;
    float* s_g = ws;                                  // 65536
    float* cm  = s_g + L_TOTAL;                       // 2048
    float* cu  = cm + N_CHUNK;                        // 2048
    float* pm  = cu + N_CHUNK;                        // 2049 (+pad)
    float* pu  = pm + (N_CHUNK + 16);                 // 2049 (+pad)
    float* cw  = pu + (N_CHUNK + 16);                 // 2048*256
    float* pwl = cw + (size_t)N_CHUNK * D_DIM;        // 2048*256
    float* T   = pwl + (size_t)N_CHUNK * D_DIM;       // 64*256
    float* sw  = T + (size_t)N_SUPER * D_DIM;         // 64*256

    kA_aggregate<<<N_CHUNK, 256, 0, stream>>>(K, V, q, s_g, cm, cu, cw);
    kB_scalar_scan<<<1, 256, 0, stream>>>(cm, cu, pm, pu);
    kC_super_scan<<<N_SUPER, 256, 0, stream>>>(cm, cw, pm, pwl, T);
    kD_top_scan<<<1, 256, 0, stream>>>(pm, T, sw);
    kF_output<<<N_CHUNK, 256, 0, stream>>>(V, s_g, pm, pu, pwl, sw, out);
}